// Round 9
// baseline (5187.954 us; speedup 1.0000x reference)
//
#include <hip/hip_runtime.h>
#include <hip/hip_bf16.h>

#define N_NODES 100000
#define N_EDGES 1600000
#define FEAT 128
#define N_GRAPHS 1024
#define NBUCK 391   // ceil(N_NODES/256) windows of 256 nodes (bucket = dst >> 8)
#define CHUNK 4096  // edges per k_bucket block
#define NP (N_NODES + 1)   // u rows per panel (+1 zero dummy row)
#define NGROUP 25000       // node groups of 4 per panel

typedef short short8 __attribute__((ext_vector_type(8)));
typedef float float4v __attribute__((ext_vector_type(4)));

static __device__ inline unsigned short f2bf(float f) {
    __hip_bfloat16 b = __float2bfloat16(f);
    unsigned short r;
    __builtin_memcpy(&r, &b, 2);
    return r;
}
static __device__ inline float bf_lo(unsigned int v) { return __uint_as_float(v << 16); }
static __device__ inline float bf_hi(unsigned int v) { return __uint_as_float(v & 0xFFFF0000u); }
static __device__ inline float bf_s(unsigned short s) { return __uint_as_float(((unsigned)s) << 16); }

// ---------------- fused prep: split W1/W2 hi/lo bf16 (transposed+swizzled); zero bcount, u dummy rows, tickets ----
__global__ __launch_bounds__(256) void k_prep(const float* __restrict__ W1,
                                              const float* __restrict__ W2,
                                              unsigned short* __restrict__ wp1,
                                              unsigned short* __restrict__ wp2,
                                              int* __restrict__ bcount,
                                              unsigned int* __restrict__ u,
                                              int* __restrict__ tickets) {
    int bid = blockIdx.x;
    const float* W = (bid < 64) ? W1 : W2;
    unsigned short* wp = (bid < 64) ? wp1 : wp2;
    int t = (bid & 63) * 256 + threadIdx.x;  // 0..16383
    int k = t >> 7, n = t & 127;
    float w = W[k * 128 + n];
    unsigned ub = __float_as_uint(w);
    unsigned short hi = (unsigned short)(ub >> 16);  // truncation split
    float hif = __uint_as_float(ub & 0xFFFF0000u);
    unsigned short lo = f2bf(w - hif);               // RNE residual
    int sidx = n * 128 + ((k & 7) | (8 * (((k >> 3) ^ n) & 15)));
    wp[sidx] = hi;
    wp[16384 + sidx] = lo;
    if (bid == 0) {
        for (int i = threadIdx.x; i < NBUCK; i += 256) bcount[i] = 0;
        if (threadIdx.x < 64) {  // zero dummy row of each u panel
            int p = threadIdx.x >> 3, ui = threadIdx.x & 7;
            u[((size_t)p * NP + N_NODES) * 8 + ui] = 0u;
        }
        if (threadIdx.x < 16) tickets[threadIdx.x] = 0;
    }
}

// ---------------- bucket histogram (LDS-staged) ----------------
__global__ __launch_bounds__(256) void k_hist(const int* __restrict__ dst,
                                              int* __restrict__ bcount) {
    __shared__ int h[NBUCK];
    for (int i = threadIdx.x; i < NBUCK; i += 256) h[i] = 0;
    __syncthreads();
    for (int e = blockIdx.x * 256 + threadIdx.x; e < N_EDGES; e += gridDim.x * 256)
        atomicAdd(&h[dst[e] >> 8], 1);
    __syncthreads();
    for (int i = threadIdx.x; i < NBUCK; i += 256) {
        int c = h[i];
        if (c) atomicAdd(&bcount[i], c);
    }
}

// ---------------- exclusive scan of 391 values (single block) ----------------
__global__ __launch_bounds__(512) void k_scan391(const int* __restrict__ in,
                                                 int* __restrict__ base,
                                                 int* __restrict__ cur,
                                                 int* __restrict__ tail) {
    int t = threadIdx.x;
    int v = (t < NBUCK) ? in[t] : 0;
    int lane = t & 63, wid = t >> 6;
    int s = v;
#pragma unroll
    for (int d = 1; d < 64; d <<= 1) { int n = __shfl_up(s, d); if (lane >= d) s += n; }
    __shared__ int ws[8];
    if (lane == 63) ws[wid] = s;
    __syncthreads();
    if (t < 8) {
        int x = ws[t];
#pragma unroll
        for (int d = 1; d < 8; d <<= 1) { int n = __shfl_up(x, d); if ((int)t >= d) x += n; }
        ws[t] = x;
    }
    __syncthreads();
    int excl = s - v + (wid ? ws[wid - 1] : 0);
    if (t < NBUCK) {
        base[t] = excl;
        if (cur) cur[t] = excl;
    }
    if (t == 0 && tail) tail[0] = N_EDGES;
}

// ---------------- bin edges into bucket runs (block counting-sort), packed (src<<8)|dst8 ----------------
__global__ __launch_bounds__(256) void k_bucket(const int* __restrict__ src,
                                                const int* __restrict__ dst,
                                                int* __restrict__ bcur,
                                                unsigned int* __restrict__ pairs) {
    __shared__ int cnt[NBUCK];
    __shared__ int basebuf[NBUCK];
    int t = threadIdx.x;
    int e0 = blockIdx.x * CHUNK;
    for (int i = t; i < NBUCK; i += 256) cnt[i] = 0;
    __syncthreads();
    unsigned pk[16]; int bk[16];
#pragma unroll
    for (int j = 0; j < 16; ++j) {
        int e = e0 + j * 256 + t;
        if (e < N_EDGES) {
            int s = src[e], d = dst[e];
            bk[j] = d >> 8;
            pk[j] = ((unsigned)s << 8) | (unsigned)(d & 255);
            atomicAdd(&cnt[bk[j]], 1);
        } else bk[j] = -1;
    }
    __syncthreads();
    for (int i = t; i < NBUCK; i += 256) {
        int c = cnt[i];
        basebuf[i] = c ? atomicAdd(&bcur[i], c) : 0;
        cnt[i] = 0;
    }
    __syncthreads();
#pragma unroll
    for (int j = 0; j < 16; ++j) {
        if (bk[j] >= 0) {
            int p = basebuf[bk[j]] + atomicAdd(&cnt[bk[j]], 1);
            pairs[p] = pk[j];
        }
    }
}

// ---------------- per-bucket degree via LDS atomics (+ fused dinv) ----------------
__global__ __launch_bounds__(256) void k_bdeg(const unsigned int* __restrict__ pairs,
                                              const int* __restrict__ bbase,
                                              const int* __restrict__ bcount,
                                              int* __restrict__ deg,
                                              float* __restrict__ dinv,
                                              int* __restrict__ wsum) {
    __shared__ int d[256];
    __shared__ int wr[4];
    int b = blockIdx.x, t = threadIdx.x;
    d[t] = 0;
    __syncthreads();
    int s0 = bbase[b], n = bcount[b];
    for (int i = t; i < n; i += 256) atomicAdd(&d[pairs[s0 + i] & 255u], 1);
    __syncthreads();
    int node = b * 256 + t;
    int v = d[t];
    if (node < N_NODES) {
        deg[node] = v;
        dinv[node] = rsqrtf((float)(v + 1));  // +1 self-loop
    }
#pragma unroll
    for (int dd = 32; dd > 0; dd >>= 1) v += __shfl_down(v, dd);
    if ((t & 63) == 0) wr[t >> 6] = v;
    __syncthreads();
    if (t == 0) wsum[b] = wr[0] + wr[1] + wr[2] + wr[3];
}

// ---------------- per-bucket CSR fill (L2-local scatter) ----------------
__global__ __launch_bounds__(256) void k_bfill(const unsigned int* __restrict__ pairs,
                                               const int* __restrict__ bbase,
                                               const int* __restrict__ bcount,
                                               const int* __restrict__ deg,
                                               const int* __restrict__ wbase,
                                               int* __restrict__ offs,
                                               int* __restrict__ csr) {
    __shared__ int lcur[256];
    __shared__ int ws[4];
    int b = blockIdx.x, t = threadIdx.x;
    int node = b * 256 + t;
    int dv = (node < N_NODES) ? deg[node] : 0;
    int lane = t & 63, wid = t >> 6;
    int s = dv;
#pragma unroll
    for (int d = 1; d < 64; d <<= 1) { int n = __shfl_up(s, d); if (lane >= d) s += n; }
    if (lane == 63) ws[wid] = s;
    __syncthreads();
    if (t < 4) {
        int x = ws[t];
#pragma unroll
        for (int d = 1; d < 4; d <<= 1) { int n = __shfl_up(x, d); if ((int)t >= d) x += n; }
        ws[t] = x;
    }
    __syncthreads();
    int excl = s - dv + (wid ? ws[wid - 1] : 0) + wbase[b];
    if (node < N_NODES) offs[node] = excl;
    lcur[t] = excl;
    __syncthreads();
    int s0 = bbase[b], n = bcount[b];
    for (int i = t; i < n; i += 256) {
        unsigned pr = pairs[s0 + i];
        int p = atomicAdd(&lcur[pr & 255u], 1);
        csr[p] = (int)(pr >> 8);
    }
}

// ---------------- MFMA GEMM (fp32 input): u = bf16( dinv .* (inp @ W) ), panel-major out ----------------
__global__ __launch_bounds__(256) void k_gemm_mfma(const float* __restrict__ inp,
                                                   const unsigned short* __restrict__ wp,
                                                   const float* __restrict__ dinv,
                                                   unsigned short* __restrict__ u) {
    __shared__ unsigned short sW[32768];  // 64 KB: [0..16383]=hi, [16384..]=lo (swizzled)
    {
        float4* d4 = (float4*)sW;
        const float4* s4 = (const float4*)wp;
#pragma unroll
        for (int i = 0; i < 16; ++i) d4[threadIdx.x + 256 * i] = s4[threadIdx.x + 256 * i];
    }
    __syncthreads();
    const int t = threadIdx.x;
    const int wv = t >> 6, L = t & 63;
    const int m = L & 15, q = L >> 4;
    const int r0 = blockIdx.x * 64 + wv * 16;
    int arow = r0 + m;
    if (arow >= N_NODES) arow = N_NODES - 1;
    const float4* ap = (const float4*)(inp + (size_t)arow * 128);
    float4v acc[8];
#pragma unroll
    for (int c = 0; c < 8; ++c) acc[c] = (float4v){0.f, 0.f, 0.f, 0.f};

#pragma unroll
    for (int k0 = 0; k0 < 128; k0 += 32) {
        float4 f0 = ap[(k0 >> 2) + 2 * q];
        float4 f1 = ap[(k0 >> 2) + 2 * q + 1];
        float fa[8] = {f0.x, f0.y, f0.z, f0.w, f1.x, f1.y, f1.z, f1.w};
        short8 ah, al;
#pragma unroll
        for (int j = 0; j < 8; ++j) {
            unsigned ub = __float_as_uint(fa[j]);
            ah[j] = (short)(ub >> 16);
            float hif = __uint_as_float(ub & 0xFFFF0000u);
            al[j] = (short)f2bf(fa[j] - hif);
        }
        const int b = (k0 >> 3) + q;
#pragma unroll
        for (int c = 0; c < 8; ++c) {
            int ng = c * 16 + m;
            int elem = ng * 128 + 8 * ((b ^ ng) & 15);
            short8 bh = *(const short8*)&sW[elem];
            short8 bl = *(const short8*)&sW[16384 + elem];
            acc[c] = __builtin_amdgcn_mfma_f32_16x16x32_bf16(ah, bh, acc[c], 0, 0, 0);
            acc[c] = __builtin_amdgcn_mfma_f32_16x16x32_bf16(al, bh, acc[c], 0, 0, 0);
            acc[c] = __builtin_amdgcn_mfma_f32_16x16x32_bf16(ah, bl, acc[c], 0, 0, 0);
        }
    }
#pragma unroll
    for (int r = 0; r < 4; ++r) {
        int row = r0 + 4 * q + r;
        if (row < N_NODES) {
            float dv = dinv[row];
#pragma unroll
            for (int c = 0; c < 8; ++c)
                u[((size_t)c * NP + row) * 16 + m] = f2bf(dv * acc[c][r]);  // panel c
        }
    }
}

// ---------------- MFMA GEMM (bf16 hi/lo panel-major input), panel-major out ----------------
__global__ __launch_bounds__(256) void k_gemm_mfma_bf(const unsigned short* __restrict__ hh,
                                                      const unsigned short* __restrict__ hl,
                                                      const unsigned short* __restrict__ wp,
                                                      const float* __restrict__ dinv,
                                                      unsigned short* __restrict__ u) {
    __shared__ unsigned short sW[32768];
    {
        float4* d4 = (float4*)sW;
        const float4* s4 = (const float4*)wp;
#pragma unroll
        for (int i = 0; i < 16; ++i) d4[threadIdx.x + 256 * i] = s4[threadIdx.x + 256 * i];
    }
    __syncthreads();
    const int t = threadIdx.x;
    const int wv = t >> 6, L = t & 63;
    const int m = L & 15, q = L >> 4;
    const int r0 = blockIdx.x * 64 + wv * 16;
    int arow = r0 + m;
    if (arow >= N_NODES) arow = N_NODES - 1;
    float4v acc[8];
#pragma unroll
    for (int c = 0; c < 8; ++c) acc[c] = (float4v){0.f, 0.f, 0.f, 0.f};

#pragma unroll
    for (int k0 = 0; k0 < 128; k0 += 32) {
        int c0 = k0 + 8 * q;  // A columns c0..c0+7, panel c0>>4, offset c0&15 in {0,8}
        size_t abase = ((size_t)(c0 >> 4) * N_NODES + arow) * 16 + (c0 & 15);
        short8 ah = *(const short8*)(hh + abase);
        short8 al = *(const short8*)(hl + abase);
        const int b = (k0 >> 3) + q;
#pragma unroll
        for (int c = 0; c < 8; ++c) {
            int ng = c * 16 + m;
            int elem = ng * 128 + 8 * ((b ^ ng) & 15);
            short8 bh = *(const short8*)&sW[elem];
            short8 bl = *(const short8*)&sW[16384 + elem];
            acc[c] = __builtin_amdgcn_mfma_f32_16x16x32_bf16(ah, bh, acc[c], 0, 0, 0);
            acc[c] = __builtin_amdgcn_mfma_f32_16x16x32_bf16(al, bh, acc[c], 0, 0, 0);
            acc[c] = __builtin_amdgcn_mfma_f32_16x16x32_bf16(ah, bl, acc[c], 0, 0, 0);
        }
    }
#pragma unroll
    for (int r = 0; r < 4; ++r) {
        int row = r0 + 4 * q + r;
        if (row < N_NODES) {
            float dv = dinv[row];
#pragma unroll
            for (int c = 0; c < 8; ++c)
                u[((size_t)c * NP + row) * 16 + m] = f2bf(dv * acc[c][r]);
        }
    }
}

// ---------------- panel aggregate: XCD x drains panel-x tickets (exact L2 locality via XCC_ID) -------
// u panel-major (NP rows); wave = 1 node, lanes = 8 edge-slots x 8 uints (16 feats). hlp!=null: hi/lo out.
__global__ __launch_bounds__(256) void k_aggp(const unsigned int* __restrict__ u,
                                              const int* __restrict__ offs,
                                              const int* __restrict__ csr,
                                              const float* __restrict__ dinv,
                                              const float* __restrict__ bias,
                                              unsigned int* __restrict__ hhp,
                                              unsigned int* __restrict__ hlp,
                                              int* __restrict__ tickets) {
    int xcc;
    asm volatile("s_getreg_b32 %0, hwreg(HW_REG_XCC_ID)" : "=s"(xcc));
    int myp = xcc & 7;
    __shared__ int sg;
    const int wv = threadIdx.x >> 6, L = threadIdx.x & 63;
    const int slot = L >> 3, ui = L & 7;
    for (int dp = 0; dp < 8; ++dp) {
        int p = (myp + dp) & 7;
        const unsigned int* up = u + (size_t)p * NP * 8;
        while (true) {
            __syncthreads();
            if (threadIdx.x == 0) sg = atomicAdd(&tickets[p], 1);
            __syncthreads();
            int g = sg;
            if (g >= NGROUP) break;
            int node = g * 4 + wv;
            int b0 = __builtin_amdgcn_readfirstlane(offs[node]);
            int e0 = __builtin_amdgcn_readfirstlane(offs[node + 1]);
            float ax = 0.f, ay = 0.f;
            for (int qq = b0; qq < e0; qq += 8) {
                int qi = qq + slot;
                int idx = (qi < e0) ? __builtin_nontemporal_load(&csr[qi]) : N_NODES;
                unsigned v = up[(size_t)idx * 8 + ui];
                ax += bf_lo(v); ay += bf_hi(v);
            }
            ax += __shfl_xor(ax, 8);  ay += __shfl_xor(ay, 8);
            ax += __shfl_xor(ax, 16); ay += __shfl_xor(ay, 16);
            ax += __shfl_xor(ax, 32); ay += __shfl_xor(ay, 32);
            if (L < 8) {
                unsigned sv = up[(size_t)node * 8 + L];
                ax += bf_lo(sv); ay += bf_hi(sv);
                float d = dinv[node];
                float2 bb = ((const float2*)bias)[p * 8 + L];
                float r0 = fmaxf(d * ax + bb.x, 0.f);
                float r1 = fmaxf(d * ay + bb.y, 0.f);
                size_t oi = ((size_t)p * N_NODES + node) * 8 + L;
                if (hlp) {
                    unsigned u0 = __float_as_uint(r0), u1 = __float_as_uint(r1);
                    unsigned short h0 = (unsigned short)(u0 >> 16), h1 = (unsigned short)(u1 >> 16);
                    float rf0 = __uint_as_float(u0 & 0xFFFF0000u), rf1 = __uint_as_float(u1 & 0xFFFF0000u);
                    unsigned short l0 = f2bf(r0 - rf0), l1 = f2bf(r1 - rf1);
                    __builtin_nontemporal_store((unsigned)h0 | ((unsigned)h1 << 16), &hhp[oi]);
                    __builtin_nontemporal_store((unsigned)l0 | ((unsigned)l1 << 16), &hlp[oi]);
                } else {
                    __builtin_nontemporal_store((unsigned)f2bf(r0) | ((unsigned)f2bf(r1) << 16), &hhp[oi]);
                }
            }
        }
    }
}

// ---------------- pool (batch sorted) + linear head; h = single bf16 plane, panel-major ----------------
__global__ __launch_bounds__(128) void k_pool(const unsigned short* __restrict__ hh,
                                              const int* __restrict__ batch,
                                              const float* __restrict__ Wl,
                                              const float* __restrict__ bl,
                                              float* __restrict__ out) {
    int g = blockIdx.x;
    int c = threadIdx.x;
    __shared__ int sb[2];
    if (c < 2) {
        int tgt = g + c;
        int lo = 0, hi = N_NODES;
        while (lo < hi) { int m = (lo + hi) >> 1; if (batch[m] < tgt) lo = m + 1; else hi = m; }
        sb[c] = lo;
    }
    __syncthreads();
    int s0 = sb[0], s1 = sb[1];
    const unsigned short* hp = hh + (size_t)(c >> 4) * N_NODES * 16 + (c & 15);
    float sum = 0.f;
    for (int i = s0; i < s1; ++i) sum += bf_s(hp[(size_t)i * 16]);
    float cnt = (float)(s1 - s0);
    float pooled = sum / fmaxf(cnt, 1.0f);
    __shared__ float red[128];
    float w0 = Wl[c * 2 + 0], w1 = Wl[c * 2 + 1];
    red[c] = pooled * w0;
    __syncthreads();
    for (int st = 64; st > 0; st >>= 1) { if (c < st) red[c] += red[c + st]; __syncthreads(); }
    if (c == 0) out[g * 2 + 0] = red[0] + bl[0];
    __syncthreads();
    red[c] = pooled * w1;
    __syncthreads();
    for (int st = 64; st > 0; st >>= 1) { if (c < st) red[c] += red[c + st]; __syncthreads(); }
    if (c == 0) out[g * 2 + 1] = red[0] + bl[1];
}

extern "C" void kernel_launch(void* const* d_in, const int* in_sizes, int n_in,
                              void* d_out, int out_size, void* d_ws, size_t ws_size,
                              hipStream_t stream) {
    const float* x  = (const float*)d_in[0];
    const int* ei   = (const int*)d_in[1];
    const int* batch = (const int*)d_in[2];
    const float* W1 = (const float*)d_in[3];
    const float* b1 = (const float*)d_in[4];
    const float* W2 = (const float*)d_in[5];
    const float* b2 = (const float*)d_in[6];
    const float* Wl = (const float*)d_in[7];
    const float* bl = (const float*)d_in[8];
    float* out = (float*)d_out;
    const int* src = ei;
    const int* dst = ei + N_EDGES;

    char* ws = (char*)d_ws;
    size_t o = 0;
    auto alloc = [&](size_t bytes) -> void* {
        o = (o + 255) & ~(size_t)255;
        void* p = ws + o;
        o += bytes;
        return p;
    };
    int* bcount = (int*)alloc((size_t)NBUCK * 4);
    int* bbase  = (int*)alloc((size_t)NBUCK * 4);
    int* bcur   = (int*)alloc((size_t)NBUCK * 4);
    int* wsum   = (int*)alloc((size_t)NBUCK * 4);
    int* wbase  = (int*)alloc((size_t)NBUCK * 4);
    int* tickets = (int*)alloc(64);
    int* deg    = (int*)alloc((size_t)N_NODES * 4);
    float* dinv = (float*)alloc((size_t)N_NODES * 4);
    int* offs   = (int*)alloc((size_t)(N_NODES + 1) * 4);
    unsigned short* wp1 = (unsigned short*)alloc(65536);
    unsigned short* wp2 = (unsigned short*)alloc(65536);
    unsigned int* pairs = (unsigned int*)alloc((size_t)N_EDGES * 4);
    int* csr    = (int*)alloc((size_t)(N_EDGES + 8) * 4);                  // +8 pad
    unsigned short* u = (unsigned short*)alloc((size_t)8 * NP * 16 * 2);   // panel-major + dummy rows
    unsigned short* hh = (unsigned short*)alloc((size_t)N_NODES * 128 * 2);
    unsigned short* hl = (unsigned short*)alloc((size_t)N_NODES * 128 * 2);

    k_prep<<<128, 256, 0, stream>>>(W1, W2, wp1, wp2, bcount, (unsigned int*)u, tickets);
    k_hist<<<256, 256, 0, stream>>>(dst, bcount);
    k_scan391<<<1, 512, 0, stream>>>(bcount, bbase, bcur, nullptr);
    k_bucket<<<(N_EDGES + CHUNK - 1) / CHUNK, 256, 0, stream>>>(src, dst, bcur, pairs);
    k_bdeg<<<NBUCK, 256, 0, stream>>>(pairs, bbase, bcount, deg, dinv, wsum);
    k_scan391<<<1, 512, 0, stream>>>(wsum, wbase, nullptr, &offs[N_NODES]);
    k_bfill<<<NBUCK, 256, 0, stream>>>(pairs, bbase, bcount, deg, wbase, offs, csr);

    const int gemmGrid = (N_NODES + 63) / 64;  // 1563
    k_gemm_mfma<<<gemmGrid, 256, 0, stream>>>(x, wp1, dinv, u);
    k_aggp<<<2048, 256, 0, stream>>>((const unsigned int*)u, offs, csr, dinv, b1,
                                     (unsigned int*)hh, (unsigned int*)hl, tickets);
    k_gemm_mfma_bf<<<gemmGrid, 256, 0, stream>>>(hh, hl, wp2, dinv, u);
    k_aggp<<<2048, 256, 0, stream>>>((const unsigned int*)u, offs, csr, dinv, b2,
                                     (unsigned int*)hh, nullptr, tickets + 8);

    k_pool<<<N_GRAPHS, 128, 0, stream>>>(hh, batch, Wl, bl, out);
}

// Round 10
// 1606.718 us; speedup vs baseline: 3.2289x; 3.2289x over previous
//
#include <hip/hip_runtime.h>
#include <hip/hip_bf16.h>

#define N_NODES 100000
#define N_EDGES 1600000
#define FEAT 128
#define N_GRAPHS 1024
#define NBUCK 391   // ceil(N_NODES/256) windows of 256 nodes (bucket = dst >> 8)
#define CHUNK 4096  // edges per k_bucket block
#define NP (N_NODES + 1)   // u rows per panel (+1 zero dummy row)
#define BATCH 256          // nodes per agg ticket
#define NBATCH 391         // ceil(N_NODES/BATCH)

typedef short short8 __attribute__((ext_vector_type(8)));
typedef float float4v __attribute__((ext_vector_type(4)));

static __device__ inline unsigned short f2bf(float f) {
    __hip_bfloat16 b = __float2bfloat16(f);
    unsigned short r;
    __builtin_memcpy(&r, &b, 2);
    return r;
}
static __device__ inline float bf_lo(unsigned int v) { return __uint_as_float(v << 16); }
static __device__ inline float bf_hi(unsigned int v) { return __uint_as_float(v & 0xFFFF0000u); }
static __device__ inline float bf_s(unsigned short s) { return __uint_as_float(((unsigned)s) << 16); }

// ---------------- fused prep: split W1/W2 hi/lo bf16 (transposed+swizzled); zero bcount, u dummy rows, tickets ----
__global__ __launch_bounds__(256) void k_prep(const float* __restrict__ W1,
                                              const float* __restrict__ W2,
                                              unsigned short* __restrict__ wp1,
                                              unsigned short* __restrict__ wp2,
                                              int* __restrict__ bcount,
                                              unsigned int* __restrict__ u,
                                              int* __restrict__ tickets) {
    int bid = blockIdx.x;
    const float* W = (bid < 64) ? W1 : W2;
    unsigned short* wp = (bid < 64) ? wp1 : wp2;
    int t = (bid & 63) * 256 + threadIdx.x;  // 0..16383
    int k = t >> 7, n = t & 127;
    float w = W[k * 128 + n];
    unsigned ub = __float_as_uint(w);
    unsigned short hi = (unsigned short)(ub >> 16);  // truncation split
    float hif = __uint_as_float(ub & 0xFFFF0000u);
    unsigned short lo = f2bf(w - hif);               // RNE residual
    int sidx = n * 128 + ((k & 7) | (8 * (((k >> 3) ^ n) & 15)));
    wp[sidx] = hi;
    wp[16384 + sidx] = lo;
    if (bid == 0) {
        for (int i = threadIdx.x; i < NBUCK; i += 256) bcount[i] = 0;
        if (threadIdx.x < 64) {  // zero dummy row of each u panel
            int p = threadIdx.x >> 3, ui = threadIdx.x & 7;
            u[((size_t)p * NP + N_NODES) * 8 + ui] = 0u;
        }
        if (threadIdx.x < 16) tickets[threadIdx.x] = 0;
    }
}

// ---------------- bucket histogram (LDS-staged) ----------------
__global__ __launch_bounds__(256) void k_hist(const int* __restrict__ dst,
                                              int* __restrict__ bcount) {
    __shared__ int h[NBUCK];
    for (int i = threadIdx.x; i < NBUCK; i += 256) h[i] = 0;
    __syncthreads();
    for (int e = blockIdx.x * 256 + threadIdx.x; e < N_EDGES; e += gridDim.x * 256)
        atomicAdd(&h[dst[e] >> 8], 1);
    __syncthreads();
    for (int i = threadIdx.x; i < NBUCK; i += 256) {
        int c = h[i];
        if (c) atomicAdd(&bcount[i], c);
    }
}

// ---------------- exclusive scan of 391 values (single block) ----------------
__global__ __launch_bounds__(512) void k_scan391(const int* __restrict__ in,
                                                 int* __restrict__ base,
                                                 int* __restrict__ cur,
                                                 int* __restrict__ tail) {
    int t = threadIdx.x;
    int v = (t < NBUCK) ? in[t] : 0;
    int lane = t & 63, wid = t >> 6;
    int s = v;
#pragma unroll
    for (int d = 1; d < 64; d <<= 1) { int n = __shfl_up(s, d); if (lane >= d) s += n; }
    __shared__ int ws[8];
    if (lane == 63) ws[wid] = s;
    __syncthreads();
    if (t < 8) {
        int x = ws[t];
#pragma unroll
        for (int d = 1; d < 8; d <<= 1) { int n = __shfl_up(x, d); if ((int)t >= d) x += n; }
        ws[t] = x;
    }
    __syncthreads();
    int excl = s - v + (wid ? ws[wid - 1] : 0);
    if (t < NBUCK) {
        base[t] = excl;
        if (cur) cur[t] = excl;
    }
    if (t == 0 && tail) tail[0] = N_EDGES;
}

// ---------------- bin edges into bucket runs (block counting-sort), packed (src<<8)|dst8 ----------------
__global__ __launch_bounds__(256) void k_bucket(const int* __restrict__ src,
                                                const int* __restrict__ dst,
                                                int* __restrict__ bcur,
                                                unsigned int* __restrict__ pairs) {
    __shared__ int cnt[NBUCK];
    __shared__ int basebuf[NBUCK];
    int t = threadIdx.x;
    int e0 = blockIdx.x * CHUNK;
    for (int i = t; i < NBUCK; i += 256) cnt[i] = 0;
    __syncthreads();
    unsigned pk[16]; int bk[16];
#pragma unroll
    for (int j = 0; j < 16; ++j) {
        int e = e0 + j * 256 + t;
        if (e < N_EDGES) {
            int s = src[e], d = dst[e];
            bk[j] = d >> 8;
            pk[j] = ((unsigned)s << 8) | (unsigned)(d & 255);
            atomicAdd(&cnt[bk[j]], 1);
        } else bk[j] = -1;
    }
    __syncthreads();
    for (int i = t; i < NBUCK; i += 256) {
        int c = cnt[i];
        basebuf[i] = c ? atomicAdd(&bcur[i], c) : 0;
        cnt[i] = 0;
    }
    __syncthreads();
#pragma unroll
    for (int j = 0; j < 16; ++j) {
        if (bk[j] >= 0) {
            int p = basebuf[bk[j]] + atomicAdd(&cnt[bk[j]], 1);
            pairs[p] = pk[j];
        }
    }
}

// ---------------- per-bucket degree via LDS atomics (+ fused dinv) ----------------
__global__ __launch_bounds__(256) void k_bdeg(const unsigned int* __restrict__ pairs,
                                              const int* __restrict__ bbase,
                                              const int* __restrict__ bcount,
                                              int* __restrict__ deg,
                                              float* __restrict__ dinv,
                                              int* __restrict__ wsum) {
    __shared__ int d[256];
    __shared__ int wr[4];
    int b = blockIdx.x, t = threadIdx.x;
    d[t] = 0;
    __syncthreads();
    int s0 = bbase[b], n = bcount[b];
    for (int i = t; i < n; i += 256) atomicAdd(&d[pairs[s0 + i] & 255u], 1);
    __syncthreads();
    int node = b * 256 + t;
    int v = d[t];
    if (node < N_NODES) {
        deg[node] = v;
        dinv[node] = rsqrtf((float)(v + 1));  // +1 self-loop
    }
#pragma unroll
    for (int dd = 32; dd > 0; dd >>= 1) v += __shfl_down(v, dd);
    if ((t & 63) == 0) wr[t >> 6] = v;
    __syncthreads();
    if (t == 0) wsum[b] = wr[0] + wr[1] + wr[2] + wr[3];
}

// ---------------- per-bucket CSR fill (L2-local scatter) ----------------
__global__ __launch_bounds__(256) void k_bfill(const unsigned int* __restrict__ pairs,
                                               const int* __restrict__ bbase,
                                               const int* __restrict__ bcount,
                                               const int* __restrict__ deg,
                                               const int* __restrict__ wbase,
                                               int* __restrict__ offs,
                                               int* __restrict__ csr) {
    __shared__ int lcur[256];
    __shared__ int ws[4];
    int b = blockIdx.x, t = threadIdx.x;
    int node = b * 256 + t;
    int dv = (node < N_NODES) ? deg[node] : 0;
    int lane = t & 63, wid = t >> 6;
    int s = dv;
#pragma unroll
    for (int d = 1; d < 64; d <<= 1) { int n = __shfl_up(s, d); if (lane >= d) s += n; }
    if (lane == 63) ws[wid] = s;
    __syncthreads();
    if (t < 4) {
        int x = ws[t];
#pragma unroll
        for (int d = 1; d < 4; d <<= 1) { int n = __shfl_up(x, d); if ((int)t >= d) x += n; }
        ws[t] = x;
    }
    __syncthreads();
    int excl = s - dv + (wid ? ws[wid - 1] : 0) + wbase[b];
    if (node < N_NODES) offs[node] = excl;
    lcur[t] = excl;
    __syncthreads();
    int s0 = bbase[b], n = bcount[b];
    for (int i = t; i < n; i += 256) {
        unsigned pr = pairs[s0 + i];
        int p = atomicAdd(&lcur[pr & 255u], 1);
        csr[p] = (int)(pr >> 8);
    }
}

// ---------------- MFMA GEMM (fp32 input): u = bf16( dinv .* (inp @ W) ), panel-major out ----------------
__global__ __launch_bounds__(256) void k_gemm_mfma(const float* __restrict__ inp,
                                                   const unsigned short* __restrict__ wp,
                                                   const float* __restrict__ dinv,
                                                   unsigned short* __restrict__ u) {
    __shared__ unsigned short sW[32768];  // 64 KB: [0..16383]=hi, [16384..]=lo (swizzled)
    {
        float4* d4 = (float4*)sW;
        const float4* s4 = (const float4*)wp;
#pragma unroll
        for (int i = 0; i < 16; ++i) d4[threadIdx.x + 256 * i] = s4[threadIdx.x + 256 * i];
    }
    __syncthreads();
    const int t = threadIdx.x;
    const int wv = t >> 6, L = t & 63;
    const int m = L & 15, q = L >> 4;
    const int r0 = blockIdx.x * 64 + wv * 16;
    int arow = r0 + m;
    if (arow >= N_NODES) arow = N_NODES - 1;
    const float4* ap = (const float4*)(inp + (size_t)arow * 128);
    float4v acc[8];
#pragma unroll
    for (int c = 0; c < 8; ++c) acc[c] = (float4v){0.f, 0.f, 0.f, 0.f};

#pragma unroll
    for (int k0 = 0; k0 < 128; k0 += 32) {
        float4 f0 = ap[(k0 >> 2) + 2 * q];
        float4 f1 = ap[(k0 >> 2) + 2 * q + 1];
        float fa[8] = {f0.x, f0.y, f0.z, f0.w, f1.x, f1.y, f1.z, f1.w};
        short8 ah, al;
#pragma unroll
        for (int j = 0; j < 8; ++j) {
            unsigned ub = __float_as_uint(fa[j]);
            ah[j] = (short)(ub >> 16);
            float hif = __uint_as_float(ub & 0xFFFF0000u);
            al[j] = (short)f2bf(fa[j] - hif);
        }
        const int b = (k0 >> 3) + q;
#pragma unroll
        for (int c = 0; c < 8; ++c) {
            int ng = c * 16 + m;
            int elem = ng * 128 + 8 * ((b ^ ng) & 15);
            short8 bh = *(const short8*)&sW[elem];
            short8 bl = *(const short8*)&sW[16384 + elem];
            acc[c] = __builtin_amdgcn_mfma_f32_16x16x32_bf16(ah, bh, acc[c], 0, 0, 0);
            acc[c] = __builtin_amdgcn_mfma_f32_16x16x32_bf16(al, bh, acc[c], 0, 0, 0);
            acc[c] = __builtin_amdgcn_mfma_f32_16x16x32_bf16(ah, bl, acc[c], 0, 0, 0);
        }
    }
#pragma unroll
    for (int r = 0; r < 4; ++r) {
        int row = r0 + 4 * q + r;
        if (row < N_NODES) {
            float dv = dinv[row];
#pragma unroll
            for (int c = 0; c < 8; ++c)
                u[((size_t)c * NP + row) * 16 + m] = f2bf(dv * acc[c][r]);  // panel c
        }
    }
}

// ---------------- MFMA GEMM (bf16 hi/lo panel-major input), panel-major out ----------------
__global__ __launch_bounds__(256) void k_gemm_mfma_bf(const unsigned short* __restrict__ hh,
                                                      const unsigned short* __restrict__ hl,
                                                      const unsigned short* __restrict__ wp,
                                                      const float* __restrict__ dinv,
                                                      unsigned short* __restrict__ u) {
    __shared__ unsigned short sW[32768];
    {
        float4* d4 = (float4*)sW;
        const float4* s4 = (const float4*)wp;
#pragma unroll
        for (int i = 0; i < 16; ++i) d4[threadIdx.x + 256 * i] = s4[threadIdx.x + 256 * i];
    }
    __syncthreads();
    const int t = threadIdx.x;
    const int wv = t >> 6, L = t & 63;
    const int m = L & 15, q = L >> 4;
    const int r0 = blockIdx.x * 64 + wv * 16;
    int arow = r0 + m;
    if (arow >= N_NODES) arow = N_NODES - 1;
    float4v acc[8];
#pragma unroll
    for (int c = 0; c < 8; ++c) acc[c] = (float4v){0.f, 0.f, 0.f, 0.f};

#pragma unroll
    for (int k0 = 0; k0 < 128; k0 += 32) {
        int c0 = k0 + 8 * q;  // A columns c0..c0+7: panel c0>>4, offset c0&15 in {0,8}
        size_t abase = ((size_t)(c0 >> 4) * N_NODES + arow) * 16 + (c0 & 15);
        short8 ah = *(const short8*)(hh + abase);
        short8 al = *(const short8*)(hl + abase);
        const int b = (k0 >> 3) + q;
#pragma unroll
        for (int c = 0; c < 8; ++c) {
            int ng = c * 16 + m;
            int elem = ng * 128 + 8 * ((b ^ ng) & 15);
            short8 bh = *(const short8*)&sW[elem];
            short8 bl = *(const short8*)&sW[16384 + elem];
            acc[c] = __builtin_amdgcn_mfma_f32_16x16x32_bf16(ah, bh, acc[c], 0, 0, 0);
            acc[c] = __builtin_amdgcn_mfma_f32_16x16x32_bf16(al, bh, acc[c], 0, 0, 0);
            acc[c] = __builtin_amdgcn_mfma_f32_16x16x32_bf16(ah, bl, acc[c], 0, 0, 0);
        }
    }
#pragma unroll
    for (int r = 0; r < 4; ++r) {
        int row = r0 + 4 * q + r;
        if (row < N_NODES) {
            float dv = dinv[row];
#pragma unroll
            for (int c = 0; c < 8; ++c)
                u[((size_t)c * NP + row) * 16 + m] = f2bf(dv * acc[c][r]);
        }
    }
}

// ---------------- panel aggregate v2: XCD-pinned panels, per-WAVE 256-node batch tickets ----------------
// No barriers in loop; 4 independent gather chains per lane; guarded atomics (plain-read precheck).
// u panel-major (NP rows, 32B/row); wave = 1 node/iter, lanes = 8 edge-slots x 8 uints (16 feats).
__global__ __launch_bounds__(256) void k_aggp(const unsigned int* __restrict__ u,
                                              const int* __restrict__ offs,
                                              const int* __restrict__ csr,
                                              const float* __restrict__ dinv,
                                              const float* __restrict__ bias,
                                              unsigned int* __restrict__ hhp,
                                              unsigned int* __restrict__ hlp,
                                              int* __restrict__ tickets) {
    int xcc;
    asm volatile("s_getreg_b32 %0, hwreg(HW_REG_XCC_ID)" : "=s"(xcc));
    int myp = xcc & 7;
    const int L = threadIdx.x & 63;
    const int slot = L >> 3, ui = L & 7;
    for (int dp = 0; dp < 8; ++dp) {
        int p = (myp + dp) & 7;
        const unsigned int* up = u + (size_t)p * NP * 8;
        while (true) {
            int t0 = NBATCH;
            if (L == 0) {
                int cur = *(volatile int*)&tickets[p];       // cheap pre-check: no atomic storm on drain
                t0 = (cur >= NBATCH) ? NBATCH : atomicAdd(&tickets[p], 1);
            }
            int tkt = __builtin_amdgcn_readfirstlane(t0);
            if (tkt >= NBATCH) break;
            int n0 = tkt * BATCH;
            int n1 = n0 + BATCH; if (n1 > N_NODES) n1 = N_NODES;
            for (int node = n0; node < n1; ++node) {
                int b0 = __builtin_amdgcn_readfirstlane(offs[node]);
                int e0 = __builtin_amdgcn_readfirstlane(offs[node + 1]);
                float ax0 = 0.f, ay0 = 0.f, ax1 = 0.f, ay1 = 0.f;
                float ax2 = 0.f, ay2 = 0.f, ax3 = 0.f, ay3 = 0.f;
                for (int qq = b0; qq < e0; qq += 32) {
                    int q0 = qq + slot;
                    int i0 = (q0      < e0) ? __builtin_nontemporal_load(&csr[q0])      : N_NODES;
                    int i1 = (q0 + 8  < e0) ? __builtin_nontemporal_load(&csr[q0 + 8])  : N_NODES;
                    int i2 = (q0 + 16 < e0) ? __builtin_nontemporal_load(&csr[q0 + 16]) : N_NODES;
                    int i3 = (q0 + 24 < e0) ? __builtin_nontemporal_load(&csr[q0 + 24]) : N_NODES;
                    unsigned v0 = up[(size_t)i0 * 8 + ui];
                    unsigned v1 = up[(size_t)i1 * 8 + ui];
                    unsigned v2 = up[(size_t)i2 * 8 + ui];
                    unsigned v3 = up[(size_t)i3 * 8 + ui];
                    ax0 += bf_lo(v0); ay0 += bf_hi(v0);
                    ax1 += bf_lo(v1); ay1 += bf_hi(v1);
                    ax2 += bf_lo(v2); ay2 += bf_hi(v2);
                    ax3 += bf_lo(v3); ay3 += bf_hi(v3);
                }
                float ax = (ax0 + ax1) + (ax2 + ax3);
                float ay = (ay0 + ay1) + (ay2 + ay3);
                ax += __shfl_xor(ax, 8);  ay += __shfl_xor(ay, 8);
                ax += __shfl_xor(ax, 16); ay += __shfl_xor(ay, 16);
                ax += __shfl_xor(ax, 32); ay += __shfl_xor(ay, 32);
                if (L < 8) {
                    unsigned sv = up[(size_t)node * 8 + L];
                    ax += bf_lo(sv); ay += bf_hi(sv);
                    float d = dinv[node];
                    float2 bb = ((const float2*)bias)[p * 8 + L];
                    float r0 = fmaxf(d * ax + bb.x, 0.f);
                    float r1 = fmaxf(d * ay + bb.y, 0.f);
                    size_t oi = ((size_t)p * N_NODES + node) * 8 + L;
                    if (hlp) {
                        unsigned u0 = __float_as_uint(r0), u1 = __float_as_uint(r1);
                        unsigned short h0 = (unsigned short)(u0 >> 16), h1 = (unsigned short)(u1 >> 16);
                        float rf0 = __uint_as_float(u0 & 0xFFFF0000u), rf1 = __uint_as_float(u1 & 0xFFFF0000u);
                        unsigned short l0 = f2bf(r0 - rf0), l1 = f2bf(r1 - rf1);
                        hhp[oi] = (unsigned)h0 | ((unsigned)h1 << 16);
                        hlp[oi] = (unsigned)l0 | ((unsigned)l1 << 16);
                    } else {
                        hhp[oi] = (unsigned)f2bf(r0) | ((unsigned)f2bf(r1) << 16);
                    }
                }
            }
        }
    }
}

// ---------------- pool (batch sorted) + linear head; h = single bf16 plane, panel-major ----------------
__global__ __launch_bounds__(128) void k_pool(const unsigned short* __restrict__ hh,
                                              const int* __restrict__ batch,
                                              const float* __restrict__ Wl,
                                              const float* __restrict__ bl,
                                              float* __restrict__ out) {
    int g = blockIdx.x;
    int c = threadIdx.x;
    __shared__ int sb[2];
    if (c < 2) {
        int tgt = g + c;
        int lo = 0, hi = N_NODES;
        while (lo < hi) { int m = (lo + hi) >> 1; if (batch[m] < tgt) lo = m + 1; else hi = m; }
        sb[c] = lo;
    }
    __syncthreads();
    int s0 = sb[0], s1 = sb[1];
    const unsigned short* hp = hh + (size_t)(c >> 4) * N_NODES * 16 + (c & 15);
    float sum = 0.f;
    for (int i = s0; i < s1; ++i) sum += bf_s(hp[(size_t)i * 16]);
    float cnt = (float)(s1 - s0);
    float pooled = sum / fmaxf(cnt, 1.0f);
    __shared__ float red[128];
    float w0 = Wl[c * 2 + 0], w1 = Wl[c * 2 + 1];
    red[c] = pooled * w0;
    __syncthreads();
    for (int st = 64; st > 0; st >>= 1) { if (c < st) red[c] += red[c + st]; __syncthreads(); }
    if (c == 0) out[g * 2 + 0] = red[0] + bl[0];
    __syncthreads();
    red[c] = pooled * w1;
    __syncthreads();
    for (int st = 64; st > 0; st >>= 1) { if (c < st) red[c] += red[c + st]; __syncthreads(); }
    if (c == 0) out[g * 2 + 1] = red[0] + bl[1];
}

extern "C" void kernel_launch(void* const* d_in, const int* in_sizes, int n_in,
                              void* d_out, int out_size, void* d_ws, size_t ws_size,
                              hipStream_t stream) {
    const float* x  = (const float*)d_in[0];
    const int* ei   = (const int*)d_in[1];
    const int* batch = (const int*)d_in[2];
    const float* W1 = (const float*)d_in[3];
    const float* b1 = (const float*)d_in[4];
    const float* W2 = (const float*)d_in[5];
    const float* b2 = (const float*)d_in[6];
    const float* Wl = (const float*)d_in[7];
    const float* bl = (const float*)d_in[8];
    float* out = (float*)d_out;
    const int* src = ei;
    const int* dst = ei + N_EDGES;

    char* ws = (char*)d_ws;
    size_t o = 0;
    auto alloc = [&](size_t bytes) -> void* {
        o = (o + 255) & ~(size_t)255;
        void* p = ws + o;
        o += bytes;
        return p;
    };
    int* bcount = (int*)alloc((size_t)NBUCK * 4);
    int* bbase  = (int*)alloc((size_t)NBUCK * 4);
    int* bcur   = (int*)alloc((size_t)NBUCK * 4);
    int* wsum   = (int*)alloc((size_t)NBUCK * 4);
    int* wbase  = (int*)alloc((size_t)NBUCK * 4);
    int* tickets = (int*)alloc(64);
    int* deg    = (int*)alloc((size_t)N_NODES * 4);
    float* dinv = (float*)alloc((size_t)N_NODES * 4);
    int* offs   = (int*)alloc((size_t)(N_NODES + 1) * 4);
    unsigned short* wp1 = (unsigned short*)alloc(65536);
    unsigned short* wp2 = (unsigned short*)alloc(65536);
    unsigned int* pairs = (unsigned int*)alloc((size_t)N_EDGES * 4);
    int* csr    = (int*)alloc((size_t)(N_EDGES + 32) * 4);                 // +32 pad
    unsigned short* u = (unsigned short*)alloc((size_t)8 * NP * 16 * 2);   // panel-major + dummy rows
    unsigned short* hh = (unsigned short*)alloc((size_t)N_NODES * 128 * 2);
    unsigned short* hl = (unsigned short*)alloc((size_t)N_NODES * 128 * 2);

    k_prep<<<128, 256, 0, stream>>>(W1, W2, wp1, wp2, bcount, (unsigned int*)u, tickets);
    k_hist<<<256, 256, 0, stream>>>(dst, bcount);
    k_scan391<<<1, 512, 0, stream>>>(bcount, bbase, bcur, nullptr);
    k_bucket<<<(N_EDGES + CHUNK - 1) / CHUNK, 256, 0, stream>>>(src, dst, bcur, pairs);
    k_bdeg<<<NBUCK, 256, 0, stream>>>(pairs, bbase, bcount, deg, dinv, wsum);
    k_scan391<<<1, 512, 0, stream>>>(wsum, wbase, nullptr, &offs[N_NODES]);
    k_bfill<<<NBUCK, 256, 0, stream>>>(pairs, bbase, bcount, deg, wbase, offs, csr);

    const int gemmGrid = (N_NODES + 63) / 64;  // 1563
    k_gemm_mfma<<<gemmGrid, 256, 0, stream>>>(x, wp1, dinv, u);
    k_aggp<<<2048, 256, 0, stream>>>((const unsigned int*)u, offs, csr, dinv, b1,
                                     (unsigned int*)hh, (unsigned int*)hl, tickets);
    k_gemm_mfma_bf<<<gemmGrid, 256, 0, stream>>>(hh, hl, wp2, dinv, u);
    k_aggp<<<2048, 256, 0, stream>>>((const unsigned int*)u, offs, csr, dinv, b2,
                                     (unsigned int*)hh, nullptr, tickets + 8);

    k_pool<<<N_GRAPHS, 128, 0, stream>>>(hh, batch, Wl, bl, out);
}

// Round 11
// 362.592 us; speedup vs baseline: 14.3080x; 4.4312x over previous
//
#include <hip/hip_runtime.h>
#include <hip/hip_bf16.h>

#define N_NODES 100000
#define N_EDGES 1600000
#define FEAT 128
#define N_GRAPHS 1024
#define NBUCK 391   // ceil(N_NODES/256) windows of 256 nodes (bucket = dst >> 8)
#define CHUNK 4096  // edges per k_bucket block

typedef short short8 __attribute__((ext_vector_type(8)));
typedef float float4v __attribute__((ext_vector_type(4)));

static __device__ inline unsigned short f2bf(float f) {
    __hip_bfloat16 b = __float2bfloat16(f);
    unsigned short r;
    __builtin_memcpy(&r, &b, 2);
    return r;
}
static __device__ inline float bf_lo(unsigned int v) { return __uint_as_float(v << 16); }
static __device__ inline float bf_hi(unsigned int v) { return __uint_as_float(v & 0xFFFF0000u); }
static __device__ inline float bf_s(unsigned short s) { return __uint_as_float(((unsigned)s) << 16); }

// ---------------- fused prep: split W1/W2 to hi/lo bf16 (transposed+swizzled), zero bcount + u dummy row ----
__global__ __launch_bounds__(256) void k_prep(const float* __restrict__ W1,
                                              const float* __restrict__ W2,
                                              unsigned short* __restrict__ wp1,
                                              unsigned short* __restrict__ wp2,
                                              int* __restrict__ bcount,
                                              unsigned int* __restrict__ udummy) {
    int bid = blockIdx.x;
    const float* W = (bid < 64) ? W1 : W2;
    unsigned short* wp = (bid < 64) ? wp1 : wp2;
    int t = (bid & 63) * 256 + threadIdx.x;  // 0..16383
    int k = t >> 7, n = t & 127;
    float w = W[k * 128 + n];
    unsigned ub = __float_as_uint(w);
    unsigned short hi = (unsigned short)(ub >> 16);  // truncation split
    float hif = __uint_as_float(ub & 0xFFFF0000u);
    unsigned short lo = f2bf(w - hif);               // RNE residual
    int sidx = n * 128 + ((k & 7) | (8 * (((k >> 3) ^ n) & 15)));
    wp[sidx] = hi;
    wp[16384 + sidx] = lo;
    if (bid == 0) {
        for (int i = threadIdx.x; i < NBUCK; i += 256) bcount[i] = 0;
        if (threadIdx.x < 64) udummy[threadIdx.x] = 0;
    }
}

// ---------------- bucket histogram (LDS-staged) ----------------
__global__ __launch_bounds__(256) void k_hist(const int* __restrict__ dst,
                                              int* __restrict__ bcount) {
    __shared__ int h[NBUCK];
    for (int i = threadIdx.x; i < NBUCK; i += 256) h[i] = 0;
    __syncthreads();
    for (int e = blockIdx.x * 256 + threadIdx.x; e < N_EDGES; e += gridDim.x * 256)
        atomicAdd(&h[dst[e] >> 8], 1);
    __syncthreads();
    for (int i = threadIdx.x; i < NBUCK; i += 256) {
        int c = h[i];
        if (c) atomicAdd(&bcount[i], c);
    }
}

// ---------------- exclusive scan of 391 values (single block) ----------------
__global__ __launch_bounds__(512) void k_scan391(const int* __restrict__ in,
                                                 int* __restrict__ base,
                                                 int* __restrict__ cur,
                                                 int* __restrict__ tail) {
    int t = threadIdx.x;
    int v = (t < NBUCK) ? in[t] : 0;
    int lane = t & 63, wid = t >> 6;
    int s = v;
#pragma unroll
    for (int d = 1; d < 64; d <<= 1) { int n = __shfl_up(s, d); if (lane >= d) s += n; }
    __shared__ int ws[8];
    if (lane == 63) ws[wid] = s;
    __syncthreads();
    if (t < 8) {
        int x = ws[t];
#pragma unroll
        for (int d = 1; d < 8; d <<= 1) { int n = __shfl_up(x, d); if ((int)t >= d) x += n; }
        ws[t] = x;
    }
    __syncthreads();
    int excl = s - v + (wid ? ws[wid - 1] : 0);
    if (t < NBUCK) {
        base[t] = excl;
        if (cur) cur[t] = excl;
    }
    if (t == 0 && tail) tail[0] = N_EDGES;
}

// ---------------- bin edges into bucket runs (block counting-sort), packed (src<<8)|dst8 ----------------
__global__ __launch_bounds__(256) void k_bucket(const int* __restrict__ src,
                                                const int* __restrict__ dst,
                                                int* __restrict__ bcur,
                                                unsigned int* __restrict__ pairs) {
    __shared__ int cnt[NBUCK];
    __shared__ int basebuf[NBUCK];
    int t = threadIdx.x;
    int e0 = blockIdx.x * CHUNK;
    for (int i = t; i < NBUCK; i += 256) cnt[i] = 0;
    __syncthreads();
    unsigned pk[16]; int bk[16];
#pragma unroll
    for (int j = 0; j < 16; ++j) {
        int e = e0 + j * 256 + t;
        if (e < N_EDGES) {
            int s = src[e], d = dst[e];
            bk[j] = d >> 8;
            pk[j] = ((unsigned)s << 8) | (unsigned)(d & 255);
            atomicAdd(&cnt[bk[j]], 1);
        } else bk[j] = -1;
    }
    __syncthreads();
    for (int i = t; i < NBUCK; i += 256) {
        int c = cnt[i];
        basebuf[i] = c ? atomicAdd(&bcur[i], c) : 0;
        cnt[i] = 0;
    }
    __syncthreads();
#pragma unroll
    for (int j = 0; j < 16; ++j) {
        if (bk[j] >= 0) {
            int p = basebuf[bk[j]] + atomicAdd(&cnt[bk[j]], 1);
            pairs[p] = pk[j];
        }
    }
}

// ---------------- per-bucket degree via LDS atomics (+ fused dinv) ----------------
__global__ __launch_bounds__(256) void k_bdeg(const unsigned int* __restrict__ pairs,
                                              const int* __restrict__ bbase,
                                              const int* __restrict__ bcount,
                                              int* __restrict__ deg,
                                              float* __restrict__ dinv,
                                              int* __restrict__ wsum) {
    __shared__ int d[256];
    __shared__ int wr[4];
    int b = blockIdx.x, t = threadIdx.x;
    d[t] = 0;
    __syncthreads();
    int s0 = bbase[b], n = bcount[b];
    for (int i = t; i < n; i += 256) atomicAdd(&d[pairs[s0 + i] & 255u], 1);
    __syncthreads();
    int node = b * 256 + t;
    int v = d[t];
    if (node < N_NODES) {
        deg[node] = v;
        dinv[node] = rsqrtf((float)(v + 1));  // +1 self-loop
    }
#pragma unroll
    for (int dd = 32; dd > 0; dd >>= 1) v += __shfl_down(v, dd);
    if ((t & 63) == 0) wr[t >> 6] = v;
    __syncthreads();
    if (t == 0) wsum[b] = wr[0] + wr[1] + wr[2] + wr[3];
}

// ---------------- per-bucket CSR fill (L2-local scatter) ----------------
__global__ __launch_bounds__(256) void k_bfill(const unsigned int* __restrict__ pairs,
                                               const int* __restrict__ bbase,
                                               const int* __restrict__ bcount,
                                               const int* __restrict__ deg,
                                               const int* __restrict__ wbase,
                                               int* __restrict__ offs,
                                               int* __restrict__ csr) {
    __shared__ int lcur[256];
    __shared__ int ws[4];
    int b = blockIdx.x, t = threadIdx.x;
    int node = b * 256 + t;
    int dv = (node < N_NODES) ? deg[node] : 0;
    int lane = t & 63, wid = t >> 6;
    int s = dv;
#pragma unroll
    for (int d = 1; d < 64; d <<= 1) { int n = __shfl_up(s, d); if (lane >= d) s += n; }
    if (lane == 63) ws[wid] = s;
    __syncthreads();
    if (t < 4) {
        int x = ws[t];
#pragma unroll
        for (int d = 1; d < 4; d <<= 1) { int n = __shfl_up(x, d); if ((int)t >= d) x += n; }
        ws[t] = x;
    }
    __syncthreads();
    int excl = s - dv + (wid ? ws[wid - 1] : 0) + wbase[b];
    if (node < N_NODES) offs[node] = excl;
    lcur[t] = excl;
    __syncthreads();
    int s0 = bbase[b], n = bcount[b];
    for (int i = t; i < n; i += 256) {
        unsigned pr = pairs[s0 + i];
        int p = atomicAdd(&lcur[pr & 255u], 1);
        csr[p] = (int)(pr >> 8);
    }
}

// ---------------- MFMA GEMM (fp32 input): u = bf16( dinv .* (inp @ W) ) ----------------
__global__ __launch_bounds__(256) void k_gemm_mfma(const float* __restrict__ inp,
                                                   const unsigned short* __restrict__ wp,
                                                   const float* __restrict__ dinv,
                                                   unsigned short* __restrict__ u) {
    __shared__ unsigned short sW[32768];  // 64 KB: [0..16383]=hi, [16384..]=lo (swizzled)
    {
        float4* d4 = (float4*)sW;
        const float4* s4 = (const float4*)wp;
#pragma unroll
        for (int i = 0; i < 16; ++i) d4[threadIdx.x + 256 * i] = s4[threadIdx.x + 256 * i];
    }
    __syncthreads();
    const int t = threadIdx.x;
    const int wv = t >> 6, L = t & 63;
    const int m = L & 15, q = L >> 4;
    const int r0 = blockIdx.x * 64 + wv * 16;
    int arow = r0 + m;
    if (arow >= N_NODES) arow = N_NODES - 1;
    const float4* ap = (const float4*)(inp + (size_t)arow * 128);
    float4v acc[8];
#pragma unroll
    for (int c = 0; c < 8; ++c) acc[c] = (float4v){0.f, 0.f, 0.f, 0.f};

#pragma unroll
    for (int k0 = 0; k0 < 128; k0 += 32) {
        float4 f0 = ap[(k0 >> 2) + 2 * q];
        float4 f1 = ap[(k0 >> 2) + 2 * q + 1];
        float fa[8] = {f0.x, f0.y, f0.z, f0.w, f1.x, f1.y, f1.z, f1.w};
        short8 ah, al;
#pragma unroll
        for (int j = 0; j < 8; ++j) {
            unsigned ub = __float_as_uint(fa[j]);
            ah[j] = (short)(ub >> 16);
            float hif = __uint_as_float(ub & 0xFFFF0000u);
            al[j] = (short)f2bf(fa[j] - hif);
        }
        const int b = (k0 >> 3) + q;
#pragma unroll
        for (int c = 0; c < 8; ++c) {
            int ng = c * 16 + m;
            int elem = ng * 128 + 8 * ((b ^ ng) & 15);
            short8 bh = *(const short8*)&sW[elem];
            short8 bl = *(const short8*)&sW[16384 + elem];
            acc[c] = __builtin_amdgcn_mfma_f32_16x16x32_bf16(ah, bh, acc[c], 0, 0, 0);
            acc[c] = __builtin_amdgcn_mfma_f32_16x16x32_bf16(al, bh, acc[c], 0, 0, 0);
            acc[c] = __builtin_amdgcn_mfma_f32_16x16x32_bf16(ah, bl, acc[c], 0, 0, 0);
        }
    }
#pragma unroll
    for (int r = 0; r < 4; ++r) {
        int row = r0 + 4 * q + r;
        if (row < N_NODES) {
            float dv = dinv[row];
            unsigned short* up = u + (size_t)row * 128 + m;
#pragma unroll
            for (int c = 0; c < 8; ++c) up[c * 16] = f2bf(dv * acc[c][r]);
        }
    }
}

// ---------------- MFMA GEMM (bf16 hi/lo plane input — no in-register split) ----------------
__global__ __launch_bounds__(256) void k_gemm_mfma_bf(const unsigned short* __restrict__ hh,
                                                      const unsigned short* __restrict__ hl,
                                                      const unsigned short* __restrict__ wp,
                                                      const float* __restrict__ dinv,
                                                      unsigned short* __restrict__ u) {
    __shared__ unsigned short sW[32768];
    {
        float4* d4 = (float4*)sW;
        const float4* s4 = (const float4*)wp;
#pragma unroll
        for (int i = 0; i < 16; ++i) d4[threadIdx.x + 256 * i] = s4[threadIdx.x + 256 * i];
    }
    __syncthreads();
    const int t = threadIdx.x;
    const int wv = t >> 6, L = t & 63;
    const int m = L & 15, q = L >> 4;
    const int r0 = blockIdx.x * 64 + wv * 16;
    int arow = r0 + m;
    if (arow >= N_NODES) arow = N_NODES - 1;
    const unsigned short* hhp = hh + (size_t)arow * 128 + 8 * q;
    const unsigned short* hlp = hl + (size_t)arow * 128 + 8 * q;
    float4v acc[8];
#pragma unroll
    for (int c = 0; c < 8; ++c) acc[c] = (float4v){0.f, 0.f, 0.f, 0.f};

#pragma unroll
    for (int k0 = 0; k0 < 128; k0 += 32) {
        short8 ah = *(const short8*)(hhp + k0);
        short8 al = *(const short8*)(hlp + k0);
        const int b = (k0 >> 3) + q;
#pragma unroll
        for (int c = 0; c < 8; ++c) {
            int ng = c * 16 + m;
            int elem = ng * 128 + 8 * ((b ^ ng) & 15);
            short8 bh = *(const short8*)&sW[elem];
            short8 bl = *(const short8*)&sW[16384 + elem];
            acc[c] = __builtin_amdgcn_mfma_f32_16x16x32_bf16(ah, bh, acc[c], 0, 0, 0);
            acc[c] = __builtin_amdgcn_mfma_f32_16x16x32_bf16(al, bh, acc[c], 0, 0, 0);
            acc[c] = __builtin_amdgcn_mfma_f32_16x16x32_bf16(ah, bl, acc[c], 0, 0, 0);
        }
    }
#pragma unroll
    for (int r = 0; r < 4; ++r) {
        int row = r0 + 4 * q + r;
        if (row < N_NODES) {
            float dv = dinv[row];
            unsigned short* up = u + (size_t)row * 128 + m;
#pragma unroll
            for (int c = 0; c < 8; ++c) up[c * 16] = f2bf(dv * acc[c][r]);
        }
    }
}

// ---------------- aggregate: h = relu(dinv*(sum u[src] + u[self]) + b) ----------------
// hlp != nullptr: emit hi/lo bf16 planes (feeds gemm2). hlp == nullptr: single bf16 plane (feeds pool).
__global__ __launch_bounds__(256) void k_agg(const unsigned int* __restrict__ u,
                                             const int* __restrict__ offs,
                                             const int* __restrict__ csr,
                                             const float* __restrict__ dinv,
                                             const float* __restrict__ bias,
                                             unsigned int* __restrict__ hhp,
                                             unsigned int* __restrict__ hlp) {
    int wid = threadIdx.x >> 6;
    int lane = threadIdx.x & 63;
    int node = __builtin_amdgcn_readfirstlane(blockIdx.x * 4 + wid);
    if (node >= N_NODES) return;
    int p = __builtin_amdgcn_readfirstlane(offs[node]);
    int e = __builtin_amdgcn_readfirstlane(offs[node + 1]);
    unsigned int self = u[(size_t)node * 64 + lane];
    float ax0 = bf_lo(self), ay0 = bf_hi(self);
    float ax1 = 0.f, ay1 = 0.f, ax2 = 0.f, ay2 = 0.f, ax3 = 0.f, ay3 = 0.f;
    float ax4 = 0.f, ay4 = 0.f, ax5 = 0.f, ay5 = 0.f, ax6 = 0.f, ay6 = 0.f;
    float ax7 = 0.f, ay7 = 0.f;
    for (; p < e; p += 8) {
        int c0 = csr[p + 0], c1 = csr[p + 1], c2 = csr[p + 2], c3 = csr[p + 3];
        int c4 = csr[p + 4], c5 = csr[p + 5], c6 = csr[p + 6], c7 = csr[p + 7];
        int i0 = c0;
        int i1 = (p + 1 < e) ? c1 : N_NODES;
        int i2 = (p + 2 < e) ? c2 : N_NODES;
        int i3 = (p + 3 < e) ? c3 : N_NODES;
        int i4 = (p + 4 < e) ? c4 : N_NODES;
        int i5 = (p + 5 < e) ? c5 : N_NODES;
        int i6 = (p + 6 < e) ? c6 : N_NODES;
        int i7 = (p + 7 < e) ? c7 : N_NODES;
        unsigned v0 = (u + (size_t)i0 * 64)[lane];
        unsigned v1 = (u + (size_t)i1 * 64)[lane];
        unsigned v2 = (u + (size_t)i2 * 64)[lane];
        unsigned v3 = (u + (size_t)i3 * 64)[lane];
        unsigned v4 = (u + (size_t)i4 * 64)[lane];
        unsigned v5 = (u + (size_t)i5 * 64)[lane];
        unsigned v6 = (u + (size_t)i6 * 64)[lane];
        unsigned v7 = (u + (size_t)i7 * 64)[lane];
        ax0 += bf_lo(v0); ay0 += bf_hi(v0);
        ax1 += bf_lo(v1); ay1 += bf_hi(v1);
        ax2 += bf_lo(v2); ay2 += bf_hi(v2);
        ax3 += bf_lo(v3); ay3 += bf_hi(v3);
        ax4 += bf_lo(v4); ay4 += bf_hi(v4);
        ax5 += bf_lo(v5); ay5 += bf_hi(v5);
        ax6 += bf_lo(v6); ay6 += bf_hi(v6);
        ax7 += bf_lo(v7); ay7 += bf_hi(v7);
    }
    float d = dinv[node];
    float2 b = ((const float2*)bias)[lane];
    float sx = ((ax0 + ax1) + (ax2 + ax3)) + ((ax4 + ax5) + (ax6 + ax7));
    float sy = ((ay0 + ay1) + (ay2 + ay3)) + ((ay4 + ay5) + (ay6 + ay7));
    float r0 = fmaxf(d * sx + b.x, 0.f);
    float r1 = fmaxf(d * sy + b.y, 0.f);
    if (hlp) {
        unsigned u0 = __float_as_uint(r0), u1 = __float_as_uint(r1);
        unsigned short h0 = (unsigned short)(u0 >> 16), h1 = (unsigned short)(u1 >> 16);
        float rf0 = __uint_as_float(u0 & 0xFFFF0000u), rf1 = __uint_as_float(u1 & 0xFFFF0000u);
        unsigned short l0 = f2bf(r0 - rf0), l1 = f2bf(r1 - rf1);
        hhp[(size_t)node * 64 + lane] = (unsigned)h0 | ((unsigned)h1 << 16);
        hlp[(size_t)node * 64 + lane] = (unsigned)l0 | ((unsigned)l1 << 16);
    } else {
        hhp[(size_t)node * 64 + lane] = (unsigned)f2bf(r0) | ((unsigned)f2bf(r1) << 16);
    }
}

// ---------------- pool (batch sorted) + linear head; h = single bf16 plane ----------------
__global__ __launch_bounds__(128) void k_pool(const unsigned short* __restrict__ hh,
                                              const int* __restrict__ batch,
                                              const float* __restrict__ Wl,
                                              const float* __restrict__ bl,
                                              float* __restrict__ out) {
    int g = blockIdx.x;
    int c = threadIdx.x;
    __shared__ int sb[2];
    if (c < 2) {
        int tgt = g + c;
        int lo = 0, hi = N_NODES;
        while (lo < hi) { int m = (lo + hi) >> 1; if (batch[m] < tgt) lo = m + 1; else hi = m; }
        sb[c] = lo;
    }
    __syncthreads();
    int s0 = sb[0], s1 = sb[1];
    float sum = 0.f;
    for (int i = s0; i < s1; ++i) sum += bf_s(hh[(size_t)i * 128 + c]);
    float cnt = (float)(s1 - s0);
    float pooled = sum / fmaxf(cnt, 1.0f);
    __shared__ float red[128];
    float w0 = Wl[c * 2 + 0], w1 = Wl[c * 2 + 1];
    red[c] = pooled * w0;
    __syncthreads();
    for (int st = 64; st > 0; st >>= 1) { if (c < st) red[c] += red[c + st]; __syncthreads(); }
    if (c == 0) out[g * 2 + 0] = red[0] + bl[0];
    __syncthreads();
    red[c] = pooled * w1;
    __syncthreads();
    for (int st = 64; st > 0; st >>= 1) { if (c < st) red[c] += red[c + st]; __syncthreads(); }
    if (c == 0) out[g * 2 + 1] = red[0] + bl[1];
}

extern "C" void kernel_launch(void* const* d_in, const int* in_sizes, int n_in,
                              void* d_out, int out_size, void* d_ws, size_t ws_size,
                              hipStream_t stream) {
    const float* x  = (const float*)d_in[0];
    const int* ei   = (const int*)d_in[1];
    const int* batch = (const int*)d_in[2];
    const float* W1 = (const float*)d_in[3];
    const float* b1 = (const float*)d_in[4];
    const float* W2 = (const float*)d_in[5];
    const float* b2 = (const float*)d_in[6];
    const float* Wl = (const float*)d_in[7];
    const float* bl = (const float*)d_in[8];
    float* out = (float*)d_out;
    const int* src = ei;
    const int* dst = ei + N_EDGES;

    char* ws = (char*)d_ws;
    size_t o = 0;
    auto alloc = [&](size_t bytes) -> void* {
        o = (o + 255) & ~(size_t)255;
        void* p = ws + o;
        o += bytes;
        return p;
    };
    int* bcount = (int*)alloc((size_t)NBUCK * 4);
    int* bbase  = (int*)alloc((size_t)NBUCK * 4);
    int* bcur   = (int*)alloc((size_t)NBUCK * 4);
    int* wsum   = (int*)alloc((size_t)NBUCK * 4);
    int* wbase  = (int*)alloc((size_t)NBUCK * 4);
    int* deg    = (int*)alloc((size_t)N_NODES * 4);
    float* dinv = (float*)alloc((size_t)N_NODES * 4);
    int* offs   = (int*)alloc((size_t)(N_NODES + 1) * 4);
    unsigned short* wp1 = (unsigned short*)alloc(65536);
    unsigned short* wp2 = (unsigned short*)alloc(65536);
    unsigned int* pairs = (unsigned int*)alloc((size_t)N_EDGES * 4);
    int* csr    = (int*)alloc((size_t)(N_EDGES + 8) * 4);               // +8 pad for unroll reads
    unsigned short* u = (unsigned short*)alloc((size_t)(N_NODES + 1) * 128 * 2);  // +1 zero row
    unsigned short* hh = (unsigned short*)alloc((size_t)N_NODES * 128 * 2);
    unsigned short* hl = (unsigned short*)alloc((size_t)N_NODES * 128 * 2);

    k_prep<<<128, 256, 0, stream>>>(W1, W2, wp1, wp2, bcount,
                                    (unsigned int*)(u + (size_t)N_NODES * 128));
    k_hist<<<256, 256, 0, stream>>>(dst, bcount);
    k_scan391<<<1, 512, 0, stream>>>(bcount, bbase, bcur, nullptr);
    k_bucket<<<(N_EDGES + CHUNK - 1) / CHUNK, 256, 0, stream>>>(src, dst, bcur, pairs);
    k_bdeg<<<NBUCK, 256, 0, stream>>>(pairs, bbase, bcount, deg, dinv, wsum);
    k_scan391<<<1, 512, 0, stream>>>(wsum, wbase, nullptr, &offs[N_NODES]);
    k_bfill<<<NBUCK, 256, 0, stream>>>(pairs, bbase, bcount, deg, wbase, offs, csr);

    const int gemmGrid = (N_NODES + 63) / 64;  // 1563
    k_gemm_mfma<<<gemmGrid, 256, 0, stream>>>(x, wp1, dinv, u);
    k_agg<<<(N_NODES + 3) / 4, 256, 0, stream>>>((const unsigned int*)u, offs, csr, dinv, b1,
                                                 (unsigned int*)hh, (unsigned int*)hl);
    k_gemm_mfma_bf<<<gemmGrid, 256, 0, stream>>>(hh, hl, wp2, dinv, u);
    k_agg<<<(N_NODES + 3) / 4, 256, 0, stream>>>((const unsigned int*)u, offs, csr, dinv, b2,
                                                 (unsigned int*)hh, nullptr);

    k_pool<<<N_GRAPHS, 128, 0, stream>>>(hh, batch, Wl, bl, out);
}

// Round 12
// 352.187 us; speedup vs baseline: 14.7307x; 1.0295x over previous
//
#include <hip/hip_runtime.h>
#include <hip/hip_bf16.h>

#define N_NODES 100000
#define N_EDGES 1600000
#define FEAT 128
#define N_GRAPHS 1024
#define NBUCK 391   // ceil(N_NODES/256) windows of 256 nodes (bucket = dst >> 8)
#define CHUNK 4096  // edges per k_bucket block
#define NTILES 1563 // ceil(N_NODES/64) gemm row tiles
#define G1A 781     // gemm1 tiles overlapped with bucket
#define G1B 782     // gemm1 tiles overlapped with bfill

typedef short short8 __attribute__((ext_vector_type(8)));
typedef float float4v __attribute__((ext_vector_type(4)));

static __device__ inline unsigned short f2bf(float f) {
    __hip_bfloat16 b = __float2bfloat16(f);
    unsigned short r;
    __builtin_memcpy(&r, &b, 2);
    return r;
}
static __device__ inline float bf_lo(unsigned int v) { return __uint_as_float(v << 16); }
static __device__ inline float bf_hi(unsigned int v) { return __uint_as_float(v & 0xFFFF0000u); }
static __device__ inline float bf_s(unsigned short s) { return __uint_as_float(((unsigned)s) << 16); }

// ---------------- dispatch 1: W-split prep (blocks 0..127) + dst histogram (blocks 128..383) ----------
__global__ __launch_bounds__(256) void k_prep_hist(const float* __restrict__ W1,
                                                   const float* __restrict__ W2,
                                                   unsigned short* __restrict__ wp1,
                                                   unsigned short* __restrict__ wp2,
                                                   const int* __restrict__ dst,
                                                   int* __restrict__ bcount,
                                                   unsigned int* __restrict__ udummy,
                                                   float* __restrict__ dinv) {
    int bid = blockIdx.x;
    if (bid < 128) {
        const float* W = (bid < 64) ? W1 : W2;
        unsigned short* wp = (bid < 64) ? wp1 : wp2;
        int t = (bid & 63) * 256 + threadIdx.x;  // 0..16383
        int k = t >> 7, n = t & 127;
        float w = W[k * 128 + n];
        unsigned ub = __float_as_uint(w);
        unsigned short hi = (unsigned short)(ub >> 16);  // truncation split
        float hif = __uint_as_float(ub & 0xFFFF0000u);
        unsigned short lo = f2bf(w - hif);               // RNE residual
        int sidx = n * 128 + ((k & 7) | (8 * (((k >> 3) ^ n) & 15)));
        wp[sidx] = hi;
        wp[16384 + sidx] = lo;
        if (bid == 0) {
            if (threadIdx.x < 64) udummy[threadIdx.x] = 0;
            if (threadIdx.x == 64) dinv[N_NODES] = 0.f;
        }
    } else {
        __shared__ int h[NBUCK];
        for (int i = threadIdx.x; i < NBUCK; i += 256) h[i] = 0;
        __syncthreads();
        int hb = bid - 128;
        for (int e = hb * 256 + threadIdx.x; e < N_EDGES; e += 256 * 256)
            atomicAdd(&h[dst[e] >> 8], 1);
        __syncthreads();
        for (int i = threadIdx.x; i < NBUCK; i += 256) {
            int c = h[i];
            if (c) atomicAdd(&bcount[i], c);
        }
    }
}

// ---------------- dispatch 2: exclusive scan of 391 bucket counts (single block) ----------------
// bbase doubles as the CSR window base (wbase==bbase: per-bucket deg sum == bucket edge count).
__global__ __launch_bounds__(512) void k_scan391(const int* __restrict__ in,
                                                 int* __restrict__ base,
                                                 int* __restrict__ cur,
                                                 int* __restrict__ tail) {
    int t = threadIdx.x;
    int v = (t < NBUCK) ? in[t] : 0;
    int lane = t & 63, wid = t >> 6;
    int s = v;
#pragma unroll
    for (int d = 1; d < 64; d <<= 1) { int n = __shfl_up(s, d); if (lane >= d) s += n; }
    __shared__ int ws[8];
    if (lane == 63) ws[wid] = s;
    __syncthreads();
    if (t < 8) {
        int x = ws[t];
#pragma unroll
        for (int d = 1; d < 8; d <<= 1) { int n = __shfl_up(x, d); if ((int)t >= d) x += n; }
        ws[t] = x;
    }
    __syncthreads();
    int excl = s - v + (wid ? ws[wid - 1] : 0);
    if (t < NBUCK) {
        base[t] = excl;
        cur[t] = excl;
    }
    if (t == 0) tail[0] = N_EDGES;
}

// ---------------- shared gemm body: u = bf16(inp @ W) (UNSCALED — dinv applied in agg) ----------------
__device__ __forceinline__ void gemm_f32_body(int tile, const float* __restrict__ inp,
                                              const unsigned short* __restrict__ wp,
                                              unsigned short* __restrict__ u) {
    __shared__ unsigned short sW[32768];  // 64 KB: hi | lo (swizzled)
    {
        float4* d4 = (float4*)sW;
        const float4* s4 = (const float4*)wp;
#pragma unroll
        for (int i = 0; i < 16; ++i) d4[threadIdx.x + 256 * i] = s4[threadIdx.x + 256 * i];
    }
    __syncthreads();
    const int t = threadIdx.x;
    const int wv = t >> 6, L = t & 63;
    const int m = L & 15, q = L >> 4;
    const int r0 = tile * 64 + wv * 16;
    int arow = r0 + m;
    if (arow >= N_NODES) arow = N_NODES - 1;
    const float4* ap = (const float4*)(inp + (size_t)arow * 128);
    float4v acc[8];
#pragma unroll
    for (int c = 0; c < 8; ++c) acc[c] = (float4v){0.f, 0.f, 0.f, 0.f};
#pragma unroll
    for (int k0 = 0; k0 < 128; k0 += 32) {
        float4 f0 = ap[(k0 >> 2) + 2 * q];
        float4 f1 = ap[(k0 >> 2) + 2 * q + 1];
        float fa[8] = {f0.x, f0.y, f0.z, f0.w, f1.x, f1.y, f1.z, f1.w};
        short8 ah, al;
#pragma unroll
        for (int j = 0; j < 8; ++j) {
            unsigned ub = __float_as_uint(fa[j]);
            ah[j] = (short)(ub >> 16);
            float hif = __uint_as_float(ub & 0xFFFF0000u);
            al[j] = (short)f2bf(fa[j] - hif);
        }
        const int b = (k0 >> 3) + q;
#pragma unroll
        for (int c = 0; c < 8; ++c) {
            int ng = c * 16 + m;
            int elem = ng * 128 + 8 * ((b ^ ng) & 15);
            short8 bh = *(const short8*)&sW[elem];
            short8 bl = *(const short8*)&sW[16384 + elem];
            acc[c] = __builtin_amdgcn_mfma_f32_16x16x32_bf16(ah, bh, acc[c], 0, 0, 0);
            acc[c] = __builtin_amdgcn_mfma_f32_16x16x32_bf16(al, bh, acc[c], 0, 0, 0);
            acc[c] = __builtin_amdgcn_mfma_f32_16x16x32_bf16(ah, bl, acc[c], 0, 0, 0);
        }
    }
#pragma unroll
    for (int r = 0; r < 4; ++r) {
        int row = r0 + 4 * q + r;
        if (row < N_NODES) {
            unsigned short* up = u + (size_t)row * 128 + m;
#pragma unroll
            for (int c = 0; c < 8; ++c) up[c * 16] = f2bf(acc[c][r]);
        }
    }
}

// ---------------- dispatch 3: bucket binning (blocks 0..390) + gemm1 tiles 0..780 ----------------
__global__ __launch_bounds__(256) void k_bucket_g1(const int* __restrict__ src,
                                                   const int* __restrict__ dst,
                                                   int* __restrict__ bcur,
                                                   unsigned int* __restrict__ pairs,
                                                   const float* __restrict__ x,
                                                   const unsigned short* __restrict__ wp1,
                                                   unsigned short* __restrict__ u) {
    if (blockIdx.x >= NBUCK) {
        gemm_f32_body(blockIdx.x - NBUCK, x, wp1, u);
        return;
    }
    __shared__ int cnt[NBUCK];
    __shared__ int basebuf[NBUCK];
    int t = threadIdx.x;
    int e0 = blockIdx.x * CHUNK;
    for (int i = t; i < NBUCK; i += 256) cnt[i] = 0;
    __syncthreads();
    unsigned pk[16]; int bk[16];
#pragma unroll
    for (int j = 0; j < 16; ++j) {
        int e = e0 + j * 256 + t;
        if (e < N_EDGES) {
            int s = src[e], d = dst[e];
            bk[j] = d >> 8;
            pk[j] = ((unsigned)s << 8) | (unsigned)(d & 255);
            atomicAdd(&cnt[bk[j]], 1);
        } else bk[j] = -1;
    }
    __syncthreads();
    for (int i = t; i < NBUCK; i += 256) {
        int c = cnt[i];
        basebuf[i] = c ? atomicAdd(&bcur[i], c) : 0;
        cnt[i] = 0;
    }
    __syncthreads();
#pragma unroll
    for (int j = 0; j < 16; ++j) {
        if (bk[j] >= 0) {
            int p = basebuf[bk[j]] + atomicAdd(&cnt[bk[j]], 1);
            pairs[p] = pk[j];
        }
    }
}

// ---------------- dispatch 4: fused deg+dinv+offs+csr fill (blocks 0..390) + gemm1 tiles 781..1562 ----
__global__ __launch_bounds__(256) void k_bfill_g1(const unsigned int* __restrict__ pairs,
                                                  const int* __restrict__ bbase,
                                                  const int* __restrict__ bcount,
                                                  float* __restrict__ dinv,
                                                  int* __restrict__ offs,
                                                  int* __restrict__ csr,
                                                  const float* __restrict__ x,
                                                  const unsigned short* __restrict__ wp1,
                                                  unsigned short* __restrict__ u) {
    if (blockIdx.x >= NBUCK) {
        gemm_f32_body(blockIdx.x - NBUCK + G1A, x, wp1, u);
        return;
    }
    __shared__ int degl[256];
    __shared__ int lcur[256];
    __shared__ int ws[4];
    int b = blockIdx.x, t = threadIdx.x;
    degl[t] = 0;
    __syncthreads();
    int s0 = bbase[b], n = bcount[b];
    for (int i = t; i < n; i += 256) atomicAdd(&degl[pairs[s0 + i] & 255u], 1);
    __syncthreads();
    int node = b * 256 + t;
    int dv = degl[t];
    if (node < N_NODES) dinv[node] = rsqrtf((float)(dv + 1));  // +1 self-loop
    int lane = t & 63, wid = t >> 6;
    int s = dv;
#pragma unroll
    for (int d = 1; d < 64; d <<= 1) { int nn = __shfl_up(s, d); if (lane >= d) s += nn; }
    if (lane == 63) ws[wid] = s;
    __syncthreads();
    if (t < 4) {
        int xx = ws[t];
#pragma unroll
        for (int d = 1; d < 4; d <<= 1) { int nn = __shfl_up(xx, d); if ((int)t >= d) xx += nn; }
        ws[t] = xx;
    }
    __syncthreads();
    int excl = s - dv + (wid ? ws[wid - 1] : 0) + bbase[b];  // wbase == bbase
    if (node < N_NODES) offs[node] = excl;
    lcur[t] = excl;
    __syncthreads();
    for (int i = t; i < n; i += 256) {
        unsigned pr = pairs[s0 + i];
        int p = atomicAdd(&lcur[pr & 255u], 1);
        csr[p] = (int)(pr >> 8);
    }
}

// ---------------- gemm2: bf16 hi/lo plane input, unscaled u out ----------------
__global__ __launch_bounds__(256) void k_gemm_mfma_bf(const unsigned short* __restrict__ hh,
                                                      const unsigned short* __restrict__ hl,
                                                      const unsigned short* __restrict__ wp,
                                                      unsigned short* __restrict__ u) {
    __shared__ unsigned short sW[32768];
    {
        float4* d4 = (float4*)sW;
        const float4* s4 = (const float4*)wp;
#pragma unroll
        for (int i = 0; i < 16; ++i) d4[threadIdx.x + 256 * i] = s4[threadIdx.x + 256 * i];
    }
    __syncthreads();
    const int t = threadIdx.x;
    const int wv = t >> 6, L = t & 63;
    const int m = L & 15, q = L >> 4;
    const int r0 = blockIdx.x * 64 + wv * 16;
    int arow = r0 + m;
    if (arow >= N_NODES) arow = N_NODES - 1;
    const unsigned short* hhp = hh + (size_t)arow * 128 + 8 * q;
    const unsigned short* hlp = hl + (size_t)arow * 128 + 8 * q;
    float4v acc[8];
#pragma unroll
    for (int c = 0; c < 8; ++c) acc[c] = (float4v){0.f, 0.f, 0.f, 0.f};
#pragma unroll
    for (int k0 = 0; k0 < 128; k0 += 32) {
        short8 ah = *(const short8*)(hhp + k0);
        short8 al = *(const short8*)(hlp + k0);
        const int b = (k0 >> 3) + q;
#pragma unroll
        for (int c = 0; c < 8; ++c) {
            int ng = c * 16 + m;
            int elem = ng * 128 + 8 * ((b ^ ng) & 15);
            short8 bh = *(const short8*)&sW[elem];
            short8 bl = *(const short8*)&sW[16384 + elem];
            acc[c] = __builtin_amdgcn_mfma_f32_16x16x32_bf16(ah, bh, acc[c], 0, 0, 0);
            acc[c] = __builtin_amdgcn_mfma_f32_16x16x32_bf16(al, bh, acc[c], 0, 0, 0);
            acc[c] = __builtin_amdgcn_mfma_f32_16x16x32_bf16(ah, bl, acc[c], 0, 0, 0);
        }
    }
#pragma unroll
    for (int r = 0; r < 4; ++r) {
        int row = r0 + 4 * q + r;
        if (row < N_NODES) {
            unsigned short* up = u + (size_t)row * 128 + m;
#pragma unroll
            for (int c = 0; c < 8; ++c) up[c * 16] = f2bf(acc[c][r]);
        }
    }
}

// ---------------- aggregate: h = relu(dinv_i*(sum dinv_s*u[s] + dinv_i*u[i]) + b) ----------------
// u is UNSCALED; dinv applied per edge via scalar loads (FMA replaces ADD, same VALU count).
// hlp != nullptr: emit hi/lo bf16 planes (feeds gemm2). hlp == nullptr: single bf16 plane (pool).
__global__ __launch_bounds__(256) void k_agg(const unsigned int* __restrict__ u,
                                             const int* __restrict__ offs,
                                             const int* __restrict__ csr,
                                             const float* __restrict__ dinv,
                                             const float* __restrict__ bias,
                                             unsigned int* __restrict__ hhp,
                                             unsigned int* __restrict__ hlp) {
    int wid = threadIdx.x >> 6;
    int lane = threadIdx.x & 63;
    int node = __builtin_amdgcn_readfirstlane(blockIdx.x * 4 + wid);
    if (node >= N_NODES) return;
    int p = __builtin_amdgcn_readfirstlane(offs[node]);
    int e = __builtin_amdgcn_readfirstlane(offs[node + 1]);
    float dsf = dinv[node];
    unsigned int self = u[(size_t)node * 64 + lane];
    float ax0 = dsf * bf_lo(self), ay0 = dsf * bf_hi(self);
    float ax1 = 0.f, ay1 = 0.f, ax2 = 0.f, ay2 = 0.f, ax3 = 0.f, ay3 = 0.f;
    float ax4 = 0.f, ay4 = 0.f, ax5 = 0.f, ay5 = 0.f, ax6 = 0.f, ay6 = 0.f;
    float ax7 = 0.f, ay7 = 0.f;
    for (; p < e; p += 8) {
        int c0 = csr[p + 0], c1 = csr[p + 1], c2 = csr[p + 2], c3 = csr[p + 3];
        int c4 = csr[p + 4], c5 = csr[p + 5], c6 = csr[p + 6], c7 = csr[p + 7];
        int i0 = c0;
        int i1 = (p + 1 < e) ? c1 : N_NODES;
        int i2 = (p + 2 < e) ? c2 : N_NODES;
        int i3 = (p + 3 < e) ? c3 : N_NODES;
        int i4 = (p + 4 < e) ? c4 : N_NODES;
        int i5 = (p + 5 < e) ? c5 : N_NODES;
        int i6 = (p + 6 < e) ? c6 : N_NODES;
        int i7 = (p + 7 < e) ? c7 : N_NODES;
        float d0 = dinv[i0], d1 = dinv[i1], d2 = dinv[i2], d3 = dinv[i3];
        float d4 = dinv[i4], d5 = dinv[i5], d6 = dinv[i6], d7 = dinv[i7];
        unsigned v0 = (u + (size_t)i0 * 64)[lane];
        unsigned v1 = (u + (size_t)i1 * 64)[lane];
        unsigned v2 = (u + (size_t)i2 * 64)[lane];
        unsigned v3 = (u + (size_t)i3 * 64)[lane];
        unsigned v4 = (u + (size_t)i4 * 64)[lane];
        unsigned v5 = (u + (size_t)i5 * 64)[lane];
        unsigned v6 = (u + (size_t)i6 * 64)[lane];
        unsigned v7 = (u + (size_t)i7 * 64)[lane];
        ax0 = fmaf(d0, bf_lo(v0), ax0); ay0 = fmaf(d0, bf_hi(v0), ay0);
        ax1 = fmaf(d1, bf_lo(v1), ax1); ay1 = fmaf(d1, bf_hi(v1), ay1);
        ax2 = fmaf(d2, bf_lo(v2), ax2); ay2 = fmaf(d2, bf_hi(v2), ay2);
        ax3 = fmaf(d3, bf_lo(v3), ax3); ay3 = fmaf(d3, bf_hi(v3), ay3);
        ax4 = fmaf(d4, bf_lo(v4), ax4); ay4 = fmaf(d4, bf_hi(v4), ay4);
        ax5 = fmaf(d5, bf_lo(v5), ax5); ay5 = fmaf(d5, bf_hi(v5), ay5);
        ax6 = fmaf(d6, bf_lo(v6), ax6); ay6 = fmaf(d6, bf_hi(v6), ay6);
        ax7 = fmaf(d7, bf_lo(v7), ax7); ay7 = fmaf(d7, bf_hi(v7), ay7);
    }
    float2 b = ((const float2*)bias)[lane];
    float sx = ((ax0 + ax1) + (ax2 + ax3)) + ((ax4 + ax5) + (ax6 + ax7));
    float sy = ((ay0 + ay1) + (ay2 + ay3)) + ((ay4 + ay5) + (ay6 + ay7));
    float r0 = fmaxf(dsf * sx + b.x, 0.f);
    float r1 = fmaxf(dsf * sy + b.y, 0.f);
    if (hlp) {
        unsigned u0 = __float_as_uint(r0), u1 = __float_as_uint(r1);
        unsigned short h0 = (unsigned short)(u0 >> 16), h1 = (unsigned short)(u1 >> 16);
        float rf0 = __uint_as_float(u0 & 0xFFFF0000u), rf1 = __uint_as_float(u1 & 0xFFFF0000u);
        unsigned short l0 = f2bf(r0 - rf0), l1 = f2bf(r1 - rf1);
        hhp[(size_t)node * 64 + lane] = (unsigned)h0 | ((unsigned)h1 << 16);
        hlp[(size_t)node * 64 + lane] = (unsigned)l0 | ((unsigned)l1 << 16);
    } else {
        hhp[(size_t)node * 64 + lane] = (unsigned)f2bf(r0) | ((unsigned)f2bf(r1) << 16);
    }
}

// ---------------- pool (batch sorted) + linear head; h = single bf16 plane ----------------
__global__ __launch_bounds__(128) void k_pool(const unsigned short* __restrict__ hh,
                                              const int* __restrict__ batch,
                                              const float* __restrict__ Wl,
                                              const float* __restrict__ bl,
                                              float* __restrict__ out) {
    int g = blockIdx.x;
    int c = threadIdx.x;
    __shared__ int sb[2];
    if (c < 2) {
        int tgt = g + c;
        int lo = 0, hi = N_NODES;
        while (lo < hi) { int m = (lo + hi) >> 1; if (batch[m] < tgt) lo = m + 1; else hi = m; }
        sb[c] = lo;
    }
    __syncthreads();
    int s0 = sb[0], s1 = sb[1];
    float sum = 0.f;
    for (int i = s0; i < s1; ++i) sum += bf_s(hh[(size_t)i * 128 + c]);
    float cnt = (float)(s1 - s0);
    float pooled = sum / fmaxf(cnt, 1.0f);
    __shared__ float red[128];
    float w0 = Wl[c * 2 + 0], w1 = Wl[c * 2 + 1];
    red[c] = pooled * w0;
    __syncthreads();
    for (int st = 64; st > 0; st >>= 1) { if (c < st) red[c] += red[c + st]; __syncthreads(); }
    if (c == 0) out[g * 2 + 0] = red[0] + bl[0];
    __syncthreads();
    red[c] = pooled * w1;
    __syncthreads();
    for (int st = 64; st > 0; st >>= 1) { if (c < st) red[c] += red[c + st]; __syncthreads(); }
    if (c == 0) out[g * 2 + 1] = red[0] + bl[1];
}

extern "C" void kernel_launch(void* const* d_in, const int* in_sizes, int n_in,
                              void* d_out, int out_size, void* d_ws, size_t ws_size,
                              hipStream_t stream) {
    const float* x  = (const float*)d_in[0];
    const int* ei   = (const int*)d_in[1];
    const int* batch = (const int*)d_in[2];
    const float* W1 = (const float*)d_in[3];
    const float* b1 = (const float*)d_in[4];
    const float* W2 = (const float*)d_in[5];
    const float* b2 = (const float*)d_in[6];
    const float* Wl = (const float*)d_in[7];
    const float* bl = (const float*)d_in[8];
    float* out = (float*)d_out;
    const int* src = ei;
    const int* dst = ei + N_EDGES;

    char* ws = (char*)d_ws;
    size_t o = 0;
    auto alloc = [&](size_t bytes) -> void* {
        o = (o + 255) & ~(size_t)255;
        void* p = ws + o;
        o += bytes;
        return p;
    };
    int* bcount = (int*)alloc((size_t)NBUCK * 4);
    int* bbase  = (int*)alloc((size_t)NBUCK * 4);
    int* bcur   = (int*)alloc((size_t)NBUCK * 4);
    float* dinv = (float*)alloc((size_t)(N_NODES + 1) * 4);  // +1 zero slot for tail
    int* offs   = (int*)alloc((size_t)(N_NODES + 1) * 4);
    unsigned short* wp1 = (unsigned short*)alloc(65536);
    unsigned short* wp2 = (unsigned short*)alloc(65536);
    unsigned int* pairs = (unsigned int*)alloc((size_t)N_EDGES * 4);
    int* csr    = (int*)alloc((size_t)(N_EDGES + 8) * 4);               // +8 pad for unroll reads
    unsigned short* u = (unsigned short*)alloc((size_t)(N_NODES + 1) * 128 * 2);  // +1 zero row
    unsigned short* hh = (unsigned short*)alloc((size_t)N_NODES * 128 * 2);
    unsigned short* hl = (unsigned short*)alloc((size_t)N_NODES * 128 * 2);

    hipMemsetAsync(bcount, 0, (size_t)NBUCK * 4, stream);
    k_prep_hist<<<384, 256, 0, stream>>>(W1, W2, wp1, wp2, dst, bcount,
                                         (unsigned int*)(u + (size_t)N_NODES * 128), dinv);
    k_scan391<<<1, 512, 0, stream>>>(bcount, bbase, bcur, &offs[N_NODES]);
    k_bucket_g1<<<NBUCK + G1A, 256, 0, stream>>>(src, dst, bcur, pairs, x, wp1, u);
    k_bfill_g1<<<NBUCK + G1B, 256, 0, stream>>>(pairs, bbase, bcount, dinv, offs, csr, x, wp1, u);

    k_agg<<<(N_NODES + 3) / 4, 256, 0, stream>>>((const unsigned int*)u, offs, csr, dinv, b1,
                                                 (unsigned int*)hh, (unsigned int*)hl);
    k_gemm_mfma_bf<<<NTILES, 256, 0, stream>>>(hh, hl, wp2, u);
    k_agg<<<(N_NODES + 3) / 4, 256, 0, stream>>>((const unsigned int*)u, offs, csr, dinv, b2,
                                                 (unsigned int*)hh, nullptr);

    k_pool<<<N_GRAPHS, 128, 0, stream>>>(hh, batch, Wl, bl, out);
}